// Round 13
// baseline (230.813 us; speedup 1.0000x reference)
//
#include <hip/hip_runtime.h>
#include <math.h>

// MultiHeadAttentionEinsum  B=2, S=2048, E=1024, H=16, D=64. Inputs fp32
// (confirmed; bf16-sniff kept as insurance). Compute bf16 MFMA.
// r20: attn barrier-scope halved — 128-thread blocks (2 waves x 32 qrows,
// QBLK=64), grid 1024 = 4 blocks/CU (LDS 4x36,864 = 147.5KB fits). Same
// total waves; barriers bind 2 waves not 4; 4 independent scheduling
// domains/CU (m114 overlap). Per-wave compute bit-identical to r12.
// r19 XCD swizzle reverted (fetch -5.7x but dur +7%: attn not memory-bound).
// GEMMs/pack = r14/r17 (gload_lds depth-2 counted-vmcnt, folded detect).

#define EMBED 1024
#define SEQ   2048
#define BATCH 2
#define NH    16
#define HD    64

typedef __attribute__((ext_vector_type(8))) short bf16x8;
typedef __attribute__((ext_vector_type(4))) short bf16x4;
typedef __attribute__((ext_vector_type(4))) float f32x4;
typedef __attribute__((ext_vector_type(4))) unsigned int u32x4;

#define QSCALE 0.18033688f   // (1/sqrt(64)) * log2(e), folded into Q projection

__device__ inline unsigned short f2bf(float f) {
  unsigned int u = __builtin_bit_cast(unsigned int, f);
  u += 0x7fffu + ((u >> 16) & 1u);
  return (unsigned short)(u >> 16);
}
__device__ inline float bf2f(unsigned short s) {
  unsigned int u = ((unsigned int)s) << 16;
  return __builtin_bit_cast(float, u);
}

// one v_perm_b32: dword = [trunc_bf16(lo)] | [trunc_bf16(hi)] << 16 — proven r11/r12.
__device__ inline unsigned packbf(float lo, float hi) {
  return __builtin_amdgcn_perm(__builtin_bit_cast(unsigned int, hi),
                               __builtin_bit_cast(unsigned int, lo),
                               0x07060302u);
}

__device__ inline void async_cp16(const void* g, void* l) {
  __builtin_amdgcn_global_load_lds(
      (const __attribute__((address_space(1))) unsigned int*)g,
      (__attribute__((address_space(3))) unsigned int*)l, 16, 0, 0);
}

// ---- dtype sniff (fallback path only) ----
__global__ void detect_kernel(const unsigned int* __restrict__ xq, int* __restrict__ flag) {
  __shared__ int cnt[256];
  int t = threadIdx.x;
  unsigned int w = xq[t];
  unsigned int e = (w >> 7) & 0xFFu;
  cnt[t] = (e >= 0x70u && e <= 0x8Fu) ? 1 : 0;
  __syncthreads();
  for (int s = 128; s > 0; s >>= 1) {
    if (t < s) cnt[t] += cnt[t + s];
    __syncthreads();
  }
  if (t == 0) *flag = (cnt[0] >= 160) ? 1 : 0;
}

// ---- fused fp32->bf16 pack, self-sniffing ----
struct PackPtrs {
  const void* src[7];
  unsigned short* dst[7];
};
__global__ __launch_bounds__(256) void pack_all(PackPtrs p, int* __restrict__ flagw) {
  __shared__ int cnt[256];
  const int tl = threadIdx.x;
  {
    unsigned int w = ((const unsigned int*)p.src[0])[tl];
    unsigned int e = (w >> 7) & 0xFFu;
    cnt[tl] = (e >= 0x70u && e <= 0x8Fu) ? 1 : 0;
  }
  __syncthreads();
  for (int s = 128; s > 0; s >>= 1) {
    if (tl < s) cnt[tl] += cnt[tl + s];
    __syncthreads();
  }
  const bool isbf = (cnt[0] >= 160);
  if (blockIdx.x == 0 && tl == 0) *flagw = isbf ? 1 : 0;   // for gemm_out

  int ci = blockIdx.x * 256 + tl;
  int t, rel;
  if (ci < 1572864) { t = ci / 524288; rel = ci - t * 524288; }
  else { int r = ci - 1572864; int w = r / 131072; t = 3 + w; rel = r - w * 131072; }
  size_t off = (size_t)rel * 8;
  unsigned short* d = p.dst[t] + off;
  if (isbf) {
    *(bf16x8*)d = *(const bf16x8*)((const unsigned short*)p.src[t] + off);
  } else {
    const float* s = (const float*)p.src[t] + off;
    f32x4 f0 = *(const f32x4*)s;
    f32x4 f1 = *(const f32x4*)(s + 4);
    bf16x8 v;
#pragma unroll
    for (int e = 0; e < 4; ++e) {
      v[e] = (short)f2bf(f0[e]);
      v[4 + e] = (short)f2bf(f1[e]);
    }
    *(bf16x8*)d = v;
  }
}

// ---- fused QKV GEMM: 128x128 tile, depth-2 prefetch (3 bufs, counted vmcnt),
// grid (32, 8, 3). z=0: Q*QSCALE [B,H,S,D]; z=1: K [B,H,S,D]; z=2: V [B,H,D,S]
struct QkvArgs {
  const unsigned short* A[3];
  const unsigned short* W[3];
  unsigned short* out[3];
};
__global__ __launch_bounds__(256) void gemm_qkv(QkvArgs args) {
  // 3 bufs x 8192 shorts (As|Bs) = 49152 B; z==2 epilogue Ts (16640 shorts) reuses.
  __shared__ __align__(16) unsigned short smem[24576];

  const int z = blockIdx.z;
  const unsigned short* A = args.A[z];
  const unsigned short* Bw = args.W[z];
  unsigned short* out = args.out[z];

  const int tid = threadIdx.x, lane = tid & 63, wave = tid >> 6;
  const int wm = wave >> 1, wn = wave & 1;
  const int q = lane >> 4, c = lane & 15;
  const int m0 = blockIdx.x * 128, n0 = blockIdx.y * 128;

  f32x4 acc[4][4];
#pragma unroll
  for (int i = 0; i < 4; ++i)
#pragma unroll
    for (int j = 0; j < 4; ++j) acc[i][j] = (f32x4){0.f, 0.f, 0.f, 0.f};

  auto STAGE = [&](int buf, int k0) {   // 4 gload_lds per thread
#pragma unroll
    for (int jj = 0; jj < 2; ++jj) {
      int ci = jj * 256 + tid;
      async_cp16(A + (size_t)(m0 + (ci >> 2)) * EMBED + k0 + (ci & 3) * 8,
                 (void*)(smem + buf * 8192 + (jj * 256 + wave * 64) * 8));
      async_cp16(Bw + (size_t)(n0 + (ci >> 2)) * EMBED + k0 + (ci & 3) * 8,
                 (void*)(smem + buf * 8192 + 4096 + (jj * 256 + wave * 64) * 8));
    }
  };

  STAGE(0, 0);
  STAGE(1, 32);
  asm volatile("s_waitcnt vmcnt(4)" ::: "memory");   // buf0 ready, buf1 in flight
  __builtin_amdgcn_s_barrier();
  __builtin_amdgcn_sched_barrier(0);

  for (int kt = 0; kt < EMBED / 32; ++kt) {
    if (kt + 2 < EMBED / 32) STAGE((kt + 2) % 3, (kt + 2) * 32);
    const unsigned short* Ab = smem + (kt % 3) * 8192;
    const unsigned short* Bb = Ab + 4096;

    bf16x8 af[4], bfr[4];
#pragma unroll
    for (int i = 0; i < 4; ++i)
      af[i] = *(const bf16x8*)(Ab + (wm * 64 + i * 16 + c) * 32 + q * 8);
#pragma unroll
    for (int j = 0; j < 4; ++j)
      bfr[j] = *(const bf16x8*)(Bb + (wn * 64 + j * 16 + c) * 32 + q * 8);
#pragma unroll
    for (int i = 0; i < 4; ++i)
#pragma unroll
      for (int j = 0; j < 4; ++j)
        acc[i][j] = __builtin_amdgcn_mfma_f32_16x16x32_bf16(af[i], bfr[j], acc[i][j], 0, 0, 0);

    if (kt + 1 < EMBED / 32) {
      if (kt + 2 < EMBED / 32)
        asm volatile("s_waitcnt vmcnt(4)" ::: "memory");   // next buf done, one tile in flight
      else
        asm volatile("s_waitcnt vmcnt(0)" ::: "memory");   // last prefetch drains
      __builtin_amdgcn_s_barrier();
      __builtin_amdgcn_sched_barrier(0);
    }
  }

  if (z < 2) {
    const float sc = (z == 0) ? QSCALE : 1.0f;
#pragma unroll
    for (int i = 0; i < 4; ++i)
#pragma unroll
      for (int j = 0; j < 4; ++j)
#pragma unroll
        for (int r = 0; r < 4; ++r) {
          int m = m0 + wm * 64 + i * 16 + q * 4 + r;
          int col = n0 + wn * 64 + j * 16 + c;
          int b = m >> 11, s = m & 2047, h = col >> 6, d = col & 63;
          out[(size_t)((b * NH + h) * SEQ + s) * HD + d] = f2bf(acc[i][j][r] * sc);
        }
  } else {
    // V: transpose 128(s) x 128(d, 2 heads) tile through LDS -> [B,H,D,S]
    __syncthreads();
#pragma unroll
    for (int i = 0; i < 4; ++i)
#pragma unroll
      for (int j = 0; j < 4; ++j)
#pragma unroll
        for (int r = 0; r < 4; ++r)
          smem[(wm * 64 + i * 16 + q * 4 + r) * 130 + wn * 64 + j * 16 + c] =
              f2bf(acc[i][j][r]);
    __syncthreads();
    int n = tid >> 1;                 // 0..127 local d-col
    int sh = (tid & 1) * 64;          // s half
    int b = m0 >> 11, s0l = m0 & 2047;
    int h = blockIdx.y * 2 + (n >> 6), d = n & 63;
    unsigned short* dst = out + (size_t)((b * NH + h) * HD + d) * SEQ + s0l + sh;
#pragma unroll
    for (int g = 0; g < 8; ++g) {
      bf16x8 v;
#pragma unroll
      for (int e = 0; e < 8; ++e) v[e] = (short)smem[(sh + g * 8 + e) * 130 + n];
      *(bf16x8*)(dst + g * 8) = v;
    }
  }
}

// ---- out-projection GEMM: 128x128 tile, depth-2 prefetch, grid (32, 8) ----
__global__ __launch_bounds__(256) void gemm_out(
    const unsigned short* __restrict__ A,
    const unsigned short* __restrict__ Bw,
    const void* __restrict__ bias,
    void* __restrict__ out,
    const int* __restrict__ flagp)
{
  __shared__ __align__(16) unsigned short smem[24576];  // 3 bufs

  const int tid = threadIdx.x, lane = tid & 63, wave = tid >> 6;
  const int wm = wave >> 1, wn = wave & 1;
  const int q = lane >> 4, c = lane & 15;
  const int m0 = blockIdx.x * 128, n0 = blockIdx.y * 128;

  f32x4 acc[4][4];
#pragma unroll
  for (int i = 0; i < 4; ++i)
#pragma unroll
    for (int j = 0; j < 4; ++j) acc[i][j] = (f32x4){0.f, 0.f, 0.f, 0.f};

  auto STAGE = [&](int buf, int k0) {
#pragma unroll
    for (int jj = 0; jj < 2; ++jj) {
      int ci = jj * 256 + tid;
      async_cp16(A + (size_t)(m0 + (ci >> 2)) * EMBED + k0 + (ci & 3) * 8,
                 (void*)(smem + buf * 8192 + (jj * 256 + wave * 64) * 8));
      async_cp16(Bw + (size_t)(n0 + (ci >> 2)) * EMBED + k0 + (ci & 3) * 8,
                 (void*)(smem + buf * 8192 + 4096 + (jj * 256 + wave * 64) * 8));
    }
  };

  STAGE(0, 0);
  STAGE(1, 32);
  asm volatile("s_waitcnt vmcnt(4)" ::: "memory");
  __builtin_amdgcn_s_barrier();
  __builtin_amdgcn_sched_barrier(0);

  for (int kt = 0; kt < EMBED / 32; ++kt) {
    if (kt + 2 < EMBED / 32) STAGE((kt + 2) % 3, (kt + 2) * 32);
    const unsigned short* Ab = smem + (kt % 3) * 8192;
    const unsigned short* Bb = Ab + 4096;

    bf16x8 af[4], bfr[4];
#pragma unroll
    for (int i = 0; i < 4; ++i)
      af[i] = *(const bf16x8*)(Ab + (wm * 64 + i * 16 + c) * 32 + q * 8);
#pragma unroll
    for (int j = 0; j < 4; ++j)
      bfr[j] = *(const bf16x8*)(Bb + (wn * 64 + j * 16 + c) * 32 + q * 8);
#pragma unroll
    for (int i = 0; i < 4; ++i)
#pragma unroll
      for (int j = 0; j < 4; ++j)
        acc[i][j] = __builtin_amdgcn_mfma_f32_16x16x32_bf16(af[i], bfr[j], acc[i][j], 0, 0, 0);

    if (kt + 1 < EMBED / 32) {
      if (kt + 2 < EMBED / 32)
        asm volatile("s_waitcnt vmcnt(4)" ::: "memory");
      else
        asm volatile("s_waitcnt vmcnt(0)" ::: "memory");
      __builtin_amdgcn_s_barrier();
      __builtin_amdgcn_sched_barrier(0);
    }
  }

  const bool isbf = (*flagp != 0);
#pragma unroll
  for (int i = 0; i < 4; ++i)
#pragma unroll
    for (int j = 0; j < 4; ++j)
#pragma unroll
      for (int r = 0; r < 4; ++r) {
        int m = m0 + wm * 64 + i * 16 + q * 4 + r;
        int col = n0 + wn * 64 + j * 16 + c;
        float v = acc[i][j][r];
        v += isbf ? bf2f(((const unsigned short*)bias)[col]) : ((const float*)bias)[col];
        if (isnan(v)) v = 777.0f;     // marker
        if (isbf) ((unsigned short*)out)[(size_t)m * EMBED + col] = f2bf(v);
        else      ((float*)out)[(size_t)m * EMBED + col] = v;
      }
}

// ---- flash attention r20: 128-thread blocks (2 waves x 32 qrows, QBLK=64),
// grid (32,16,2)=1024 -> 4 blocks/CU (147.5KB LDS). Barrier binds 2 waves.
// Per-wave compute bit-identical to r12 (permuted-V, packbf, l via ones-MFMA,
// K-frag hoist). Staging: 128 threads, 4 K-rows + 4 V-rows each, static regs.
__global__ __launch_bounds__(128) void attn_kernel(
    const unsigned short* __restrict__ Qb,
    const unsigned short* __restrict__ Kb,
    const unsigned short* __restrict__ Vtb,
    unsigned short* __restrict__ Ob)
{
  __shared__ __align__(16) unsigned short Kt[2][64][72];
  __shared__ __align__(16) unsigned short Vs[2][64][72];

  const int tid = threadIdx.x;
  const int lane = tid & 63;
  const int wave = tid >> 6;        // 0..1
  const int q = lane >> 4, c = lane & 15;
  const int b = blockIdx.z, h = blockIdx.y;
  const int q0 = blockIdx.x * 64 + wave * 32;

  const unsigned short* Qh = Qb + ((size_t)(b * NH + h) * SEQ) * HD;
  const unsigned short* Kh = Kb + ((size_t)(b * NH + h) * SEQ) * HD;
  const unsigned short* Vh = Vtb + ((size_t)(b * NH + h) * HD) * SEQ;

  // Q B-operand frags for two 16-row groups (n=lane&15=qrow, k=d=quad*8+j)
  bf16x8 qflA = *(const bf16x8*)(Qh + (q0 + c) * HD + q * 8);
  bf16x8 qfhA = *(const bf16x8*)(Qh + (q0 + c) * HD + 32 + q * 8);
  bf16x8 qflB = *(const bf16x8*)(Qh + (q0 + 16 + c) * HD + q * 8);
  bf16x8 qfhB = *(const bf16x8*)(Qh + (q0 + 16 + c) * HD + 32 + q * 8);

  f32x4 oA[4], oB[4];
#pragma unroll
  for (int t = 0; t < 4; ++t) { oA[t] = (f32x4){0.f,0.f,0.f,0.f}; oB[t] = (f32x4){0.f,0.f,0.f,0.f}; }
  f32x4 lA = (f32x4){0.f,0.f,0.f,0.f}, lB = (f32x4){0.f,0.f,0.f,0.f};

  bf16x8 ones;
#pragma unroll
  for (int e = 0; e < 8; ++e) ones[e] = (short)0x3F80;

  const int r0 = tid >> 3;          // 0..15 (base row; rows r0+16i, i=0..3)
  const int t7 = tid & 7;
  const int ch0 = t7 * 8;           // source 8-elem chunk
  // permuted dest 8B-unit for source chunk m=2*t7 (second half goes to u0+2)
  const int u0 = 8 * (t7 >> 2) + 4 * (t7 & 1) + ((t7 >> 1) & 1);

  // running global pointers (tile stride: K rows 64*HD shorts, V cols 64 shorts)
  const unsigned short* kBase = Kh + (size_t)r0 * HD + ch0;
  const unsigned short* vBase = Vh + (size_t)r0 * SEQ + ch0;

  bf16x8 kr[4], vr[4];
  // prefetch + stage tile 0
#pragma unroll
  for (int i = 0; i < 4; ++i) {
    kr[i] = *(const bf16x8*)(kBase + (size_t)(16 * i) * HD);
    vr[i] = *(const bf16x8*)(vBase + (size_t)(16 * i) * SEQ);
  }
  kBase += (size_t)64 * HD;
  vBase += 64;
#pragma unroll
  for (int i = 0; i < 4; ++i) {
    *(bf16x8*)(&Kt[0][r0 + 16 * i][ch0]) = kr[i];
    bf16x4 lo = __builtin_shufflevector(vr[i], vr[i], 0, 1, 2, 3);
    bf16x4 hi = __builtin_shufflevector(vr[i], vr[i], 4, 5, 6, 7);
    *(bf16x4*)(&Vs[0][r0 + 16 * i][u0 * 4]) = lo;
    *(bf16x4*)(&Vs[0][r0 + 16 * i][u0 * 4 + 8]) = hi;
  }

  for (int kt = 0; kt < SEQ / 64; ++kt) {
    const int p = kt & 1;
    __syncthreads();
    if (kt + 1 < SEQ / 64) {        // issue next-tile loads early (latency overlap)
#pragma unroll
      for (int i = 0; i < 4; ++i) {
        kr[i] = *(const bf16x8*)(kBase + (size_t)(16 * i) * HD);
        vr[i] = *(const bf16x8*)(vBase + (size_t)(16 * i) * SEQ);
      }
      kBase += (size_t)64 * HD;
      vBase += 64;
    }

    // hoist all 8 K-frags: back-to-back LDS reads pipeline
    bf16x8 kf0[4], kf1[4];
#pragma unroll
    for (int s = 0; s < 4; ++s) {
      kf0[s] = *(const bf16x8*)(&Kt[p][s * 16 + c][q * 8]);
      kf1[s] = *(const bf16x8*)(&Kt[p][s * 16 + c][32 + q * 8]);
    }

#pragma unroll
    for (int g = 0; g < 2; ++g) {
      u32x4 pa, pb;
#pragma unroll
      for (int s2 = 0; s2 < 2; ++s2) {
        const int s = g * 2 + s2;
        f32x4 zA = {0.f, 0.f, 0.f, 0.f};
        f32x4 zB = {0.f, 0.f, 0.f, 0.f};
        zA = __builtin_amdgcn_mfma_f32_16x16x32_bf16(kf0[s], qflA, zA, 0, 0, 0);
        zA = __builtin_amdgcn_mfma_f32_16x16x32_bf16(kf1[s], qfhA, zA, 0, 0, 0);
        zB = __builtin_amdgcn_mfma_f32_16x16x32_bf16(kf0[s], qflB, zB, 0, 0, 0);
        zB = __builtin_amdgcn_mfma_f32_16x16x32_bf16(kf1[s], qfhB, zB, 0, 0, 0);
        float a0 = __builtin_amdgcn_exp2f(zA[0]);
        float a1 = __builtin_amdgcn_exp2f(zA[1]);
        float a2 = __builtin_amdgcn_exp2f(zA[2]);
        float a3 = __builtin_amdgcn_exp2f(zA[3]);
        float b0 = __builtin_amdgcn_exp2f(zB[0]);
        float b1 = __builtin_amdgcn_exp2f(zB[1]);
        float b2 = __builtin_amdgcn_exp2f(zB[2]);
        float b3 = __builtin_amdgcn_exp2f(zB[3]);
        pa[s2 * 2]     = packbf(a0, a1);   // = trunc(a0) | trunc(a1)<<16
        pa[s2 * 2 + 1] = packbf(a2, a3);
        pb[s2 * 2]     = packbf(b0, b1);
        pb[s2 * 2 + 1] = packbf(b2, b3);
      }
      bf16x8 pfA = __builtin_bit_cast(bf16x8, pa);
      bf16x8 pfB = __builtin_bit_cast(bf16x8, pb);
      __builtin_amdgcn_s_setprio(1);
      lA = __builtin_amdgcn_mfma_f32_16x16x32_bf16(pfA, ones, lA, 0, 0, 0);
      lB = __builtin_amdgcn_mfma_f32_16x16x32_bf16(pfB, ones, lB, 0, 0, 0);
#pragma unroll
      for (int t = 0; t < 4; ++t) {
        bf16x8 vf = *(const bf16x8*)(&Vs[p][t * 16 + c][(g * 4 + q) * 8]);
        oA[t] = __builtin_amdgcn_mfma_f32_16x16x32_bf16(pfA, vf, oA[t], 0, 0, 0);
        oB[t] = __builtin_amdgcn_mfma_f32_16x16x32_bf16(pfB, vf, oB[t], 0, 0, 0);
      }
      __builtin_amdgcn_s_setprio(0);
    }

    if (kt + 1 < SEQ / 64) {        // stage next tile into the other buffer
#pragma unroll
      for (int i = 0; i < 4; ++i) {
        *(bf16x8*)(&Kt[1 - p][r0 + 16 * i][ch0]) = kr[i];
        bf16x4 lo = __builtin_shufflevector(vr[i], vr[i], 0, 1, 2, 3);
        bf16x4 hi = __builtin_shufflevector(vr[i], vr[i], 4, 5, 6, 7);
        *(bf16x4*)(&Vs[1 - p][r0 + 16 * i][u0 * 4]) = lo;
        *(bf16x4*)(&Vs[1 - p][r0 + 16 * i][u0 * 4 + 8]) = hi;
      }
    }
  }

  // l lands in the same C-layout as o: lane reg r holds l for row q*4+r.
  float invA[4], invB[4];
#pragma unroll
  for (int r = 0; r < 4; ++r) { invA[r] = 1.0f / lA[r]; invB[r] = 1.0f / lB[r]; }
#pragma unroll
  for (int t = 0; t < 4; ++t)
#pragma unroll
    for (int r = 0; r < 4; ++r) {
      int col = h * HD + t * 16 + c;
      int srowA = q0 + q * 4 + r;
      float vA = oA[t][r] * invA[r];
      if (isnan(vA)) vA = 77.0f;    // marker
      Ob[((size_t)(b * SEQ + srowA)) * EMBED + col] = f2bf(vA);
      int srowB = q0 + 16 + q * 4 + r;
      float vB = oB[t][r] * invB[r];
      if (isnan(vB)) vB = 77.0f;    // marker
      Ob[((size_t)(b * SEQ + srowB)) * EMBED + col] = f2bf(vB);
    }
}

// ---- fallback GEMM (round-3 proven, direct global loads) ----
__device__ inline bf16x8 load8(const void* p, int idx, bool isbf) {
  if (isbf) return *(const bf16x8*)((const unsigned short*)p + idx);
  const float* f = (const float*)p + idx;
  bf16x8 r;
#pragma unroll
  for (int i = 0; i < 8; ++i) r[i] = (short)f2bf(f[i]);
  return r;
}
__global__ __launch_bounds__(256) void gemm_bt(
    const void* __restrict__ A, const void* __restrict__ Bw,
    const void* __restrict__ bias, void* __restrict__ out,
    const int* __restrict__ flagp, int mode, float scale)
{
  const bool isbf = (*flagp != 0);
  const bool a_isbf = isbf || (mode == 0);
  const int lane = threadIdx.x & 63;
  const int wave = threadIdx.x >> 6;
  const int tile = blockIdx.x * 4 + wave;
  const int mt = tile >> 4, nt = tile & 15;
  const int q = lane >> 4, c = lane & 15;
  const int m0 = mt * 16, n0 = nt * 64;

  f32x4 acc[4];
#pragma unroll
  for (int t = 0; t < 4; ++t) acc[t] = (f32x4){0.f, 0.f, 0.f, 0.f};

  for (int k0 = 0; k0 < EMBED; k0 += 32) {
    bf16x8 a = load8(A, (m0 + c) * EMBED + k0 + q * 8, a_isbf);
#pragma unroll
    for (int t = 0; t < 4; ++t) {
      bf16x8 b = load8(Bw, (n0 + t * 16 + c) * EMBED + k0 + q * 8, isbf);
      acc[t] = __builtin_amdgcn_mfma_f32_16x16x32_bf16(a, b, acc[t], 0, 0, 0);
    }
  }
#pragma unroll
  for (int t = 0; t < 4; ++t)
#pragma unroll
    for (int r = 0; r < 4; ++r) {
      float v = acc[t][r] * scale;
      int row = m0 + q * 4 + r, col = n0 + t * 16 + c;
      if (mode == 0) {
        v += isbf ? bf2f(((const unsigned short*)bias)[col]) : ((const float*)bias)[col];
        if (isbf) ((unsigned short*)out)[row * EMBED + col] = f2bf(v);
        else      ((float*)out)[row * EMBED + col] = v;
      } else {
        int b = row >> 11, s = row & 2047, h = col >> 6, d = col & 63;
        if (mode == 1) ((unsigned short*)out)[(((b * NH + h) * SEQ) + s) * HD + d] = f2bf(v);
        else           ((unsigned short*)out)[(((b * NH + h) * HD) + d) * SEQ + s] = f2bf(v);
      }
    }
}

extern "C" void kernel_launch(void* const* d_in, const int* in_sizes, int n_in,
                              void* d_out, int out_size, void* d_ws, size_t ws_size,
                              hipStream_t stream) {
  const void* xq = d_in[0]; const void* xk = d_in[1]; const void* xv = d_in[2];
  const void* Wq = d_in[3]; const void* Wk = d_in[4]; const void* Wv = d_in[5];
  const void* Wo = d_in[6]; const void* bo = d_in[7];

  const size_t NEL = (size_t)BATCH * SEQ * EMBED;
  const size_t WEL = (size_t)EMBED * EMBED;
  unsigned short* base = (unsigned short*)d_ws;

  unsigned short* Xq = base;
  unsigned short* Xk = Xq + NEL;
  unsigned short* Xv = Xk + NEL;
  unsigned short* Wqb = Xv + NEL;
  unsigned short* Wkb = Wqb + WEL;
  unsigned short* Wvb = Wkb + WEL;
  unsigned short* Wob = Wvb + WEL;
  unsigned short* Q  = Wob + WEL;
  unsigned short* K  = Q + NEL;
  unsigned short* Vt = K + NEL;
  unsigned short* AO = Xq;                  // alias: Xq dead after QKV GEMM
  int* flagF = (int*)(Vt + NEL);
  size_t need = ((char*)(flagF + 16)) - (char*)d_ws;

  if (ws_size >= need) {
    PackPtrs pp;
    pp.src[0] = xq; pp.src[1] = xk; pp.src[2] = xv;
    pp.src[3] = Wq; pp.src[4] = Wk; pp.src[5] = Wv; pp.src[6] = Wo;
    pp.dst[0] = Xq; pp.dst[1] = Xk; pp.dst[2] = Xv;
    pp.dst[3] = Wqb; pp.dst[4] = Wkb; pp.dst[5] = Wvb; pp.dst[6] = Wob;
    pack_all<<<8192, 256, 0, stream>>>(pp, flagF);   // self-sniffs; writes flagF

    QkvArgs qa;
    qa.A[0] = Xq; qa.A[1] = Xk; qa.A[2] = Xv;
    qa.W[0] = Wqb; qa.W[1] = Wkb; qa.W[2] = Wvb;
    qa.out[0] = Q; qa.out[1] = K; qa.out[2] = Vt;
    gemm_qkv<<<dim3(32, 8, 3), 256, 0, stream>>>(qa);
    attn_kernel<<<dim3(SEQ / 64, NH, BATCH), 128, 0, stream>>>(Q, K, Vt, AO);
    gemm_out<<<dim3(32, 8), 256, 0, stream>>>(AO, Wob, bo, d_out, flagF);
  } else {
    unsigned short* Qf  = base;
    unsigned short* Kf  = Qf + NEL;
    unsigned short* Vtf = Kf + NEL;
    unsigned short* AOf = Vtf + NEL;
    int* flag = (int*)(AOf + NEL);
    detect_kernel<<<1, 256, 0, stream>>>((const unsigned int*)xq, flag);
    dim3 gblk(1024, 1, 1);
    gemm_bt<<<gblk, 256, 0, stream>>>(xq, Wq, nullptr, Qf, flag, 1, QSCALE);
    gemm_bt<<<gblk, 256, 0, stream>>>(xk, Wk, nullptr, Kf, flag, 1, 1.0f);
    gemm_bt<<<gblk, 256, 0, stream>>>(xv, Wv, nullptr, Vtf, flag, 2, 1.0f);
    attn_kernel<<<dim3(SEQ / 64, NH, BATCH), 128, 0, stream>>>(Qf, Kf, Vtf, AOf);
    gemm_bt<<<gblk, 256, 0, stream>>>(AOf, Wo, bo, d_out, flag, 0, 1.0f);
  }
}

// Round 14
// 218.980 us; speedup vs baseline: 1.0540x; 1.0540x over previous
//
#include <hip/hip_runtime.h>
#include <math.h>

// MultiHeadAttentionEinsum  B=2, S=2048, E=1024, H=16, D=64. Inputs fp32
// (confirmed; bf16-sniff kept as insurance). Compute bf16 MFMA.
// r21: attn = r12/r17 exact (4th restructure falsified; 52.5 µs local opt).
// gemm_out re-tiled 64x128 -> grid (64,8)=512 blocks = 2/CU (was 1/CU,
// grid-starved). Same depth-2 counted-vmcnt pipeline, 3 gload/thread/STAGE.
// qkv/pack = r17 (gload_lds depth-2, folded detect).

#define EMBED 1024
#define SEQ   2048
#define BATCH 2
#define NH    16
#define HD    64

typedef __attribute__((ext_vector_type(8))) short bf16x8;
typedef __attribute__((ext_vector_type(4))) short bf16x4;
typedef __attribute__((ext_vector_type(4))) float f32x4;
typedef __attribute__((ext_vector_type(4))) unsigned int u32x4;

#define QSCALE 0.18033688f   // (1/sqrt(64)) * log2(e), folded into Q projection

__device__ inline unsigned short f2bf(float f) {
  unsigned int u = __builtin_bit_cast(unsigned int, f);
  u += 0x7fffu + ((u >> 16) & 1u);
  return (unsigned short)(u >> 16);
}
__device__ inline float bf2f(unsigned short s) {
  unsigned int u = ((unsigned int)s) << 16;
  return __builtin_bit_cast(float, u);
}

// one v_perm_b32: dword = [trunc_bf16(lo)] | [trunc_bf16(hi)] << 16 — proven r11/r12.
__device__ inline unsigned packbf(float lo, float hi) {
  return __builtin_amdgcn_perm(__builtin_bit_cast(unsigned int, hi),
                               __builtin_bit_cast(unsigned int, lo),
                               0x07060302u);
}

__device__ inline void async_cp16(const void* g, void* l) {
  __builtin_amdgcn_global_load_lds(
      (const __attribute__((address_space(1))) unsigned int*)g,
      (__attribute__((address_space(3))) unsigned int*)l, 16, 0, 0);
}

// ---- dtype sniff (fallback path only) ----
__global__ void detect_kernel(const unsigned int* __restrict__ xq, int* __restrict__ flag) {
  __shared__ int cnt[256];
  int t = threadIdx.x;
  unsigned int w = xq[t];
  unsigned int e = (w >> 7) & 0xFFu;
  cnt[t] = (e >= 0x70u && e <= 0x8Fu) ? 1 : 0;
  __syncthreads();
  for (int s = 128; s > 0; s >>= 1) {
    if (t < s) cnt[t] += cnt[t + s];
    __syncthreads();
  }
  if (t == 0) *flag = (cnt[0] >= 160) ? 1 : 0;
}

// ---- fused fp32->bf16 pack, self-sniffing ----
struct PackPtrs {
  const void* src[7];
  unsigned short* dst[7];
};
__global__ __launch_bounds__(256) void pack_all(PackPtrs p, int* __restrict__ flagw) {
  __shared__ int cnt[256];
  const int tl = threadIdx.x;
  {
    unsigned int w = ((const unsigned int*)p.src[0])[tl];
    unsigned int e = (w >> 7) & 0xFFu;
    cnt[tl] = (e >= 0x70u && e <= 0x8Fu) ? 1 : 0;
  }
  __syncthreads();
  for (int s = 128; s > 0; s >>= 1) {
    if (tl < s) cnt[tl] += cnt[tl + s];
    __syncthreads();
  }
  const bool isbf = (cnt[0] >= 160);
  if (blockIdx.x == 0 && tl == 0) *flagw = isbf ? 1 : 0;   // for gemm_out

  int ci = blockIdx.x * 256 + tl;
  int t, rel;
  if (ci < 1572864) { t = ci / 524288; rel = ci - t * 524288; }
  else { int r = ci - 1572864; int w = r / 131072; t = 3 + w; rel = r - w * 131072; }
  size_t off = (size_t)rel * 8;
  unsigned short* d = p.dst[t] + off;
  if (isbf) {
    *(bf16x8*)d = *(const bf16x8*)((const unsigned short*)p.src[t] + off);
  } else {
    const float* s = (const float*)p.src[t] + off;
    f32x4 f0 = *(const f32x4*)s;
    f32x4 f1 = *(const f32x4*)(s + 4);
    bf16x8 v;
#pragma unroll
    for (int e = 0; e < 4; ++e) {
      v[e] = (short)f2bf(f0[e]);
      v[4 + e] = (short)f2bf(f1[e]);
    }
    *(bf16x8*)d = v;
  }
}

// ---- fused QKV GEMM: 128x128 tile, depth-2 prefetch (3 bufs, counted vmcnt),
// grid (32, 8, 3). z=0: Q*QSCALE [B,H,S,D]; z=1: K [B,H,S,D]; z=2: V [B,H,D,S]
struct QkvArgs {
  const unsigned short* A[3];
  const unsigned short* W[3];
  unsigned short* out[3];
};
__global__ __launch_bounds__(256) void gemm_qkv(QkvArgs args) {
  // 3 bufs x 8192 shorts (As|Bs) = 49152 B; z==2 epilogue Ts (16640 shorts) reuses.
  __shared__ __align__(16) unsigned short smem[24576];

  const int z = blockIdx.z;
  const unsigned short* A = args.A[z];
  const unsigned short* Bw = args.W[z];
  unsigned short* out = args.out[z];

  const int tid = threadIdx.x, lane = tid & 63, wave = tid >> 6;
  const int wm = wave >> 1, wn = wave & 1;
  const int q = lane >> 4, c = lane & 15;
  const int m0 = blockIdx.x * 128, n0 = blockIdx.y * 128;

  f32x4 acc[4][4];
#pragma unroll
  for (int i = 0; i < 4; ++i)
#pragma unroll
    for (int j = 0; j < 4; ++j) acc[i][j] = (f32x4){0.f, 0.f, 0.f, 0.f};

  auto STAGE = [&](int buf, int k0) {   // 4 gload_lds per thread
#pragma unroll
    for (int jj = 0; jj < 2; ++jj) {
      int ci = jj * 256 + tid;
      async_cp16(A + (size_t)(m0 + (ci >> 2)) * EMBED + k0 + (ci & 3) * 8,
                 (void*)(smem + buf * 8192 + (jj * 256 + wave * 64) * 8));
      async_cp16(Bw + (size_t)(n0 + (ci >> 2)) * EMBED + k0 + (ci & 3) * 8,
                 (void*)(smem + buf * 8192 + 4096 + (jj * 256 + wave * 64) * 8));
    }
  };

  STAGE(0, 0);
  STAGE(1, 32);
  asm volatile("s_waitcnt vmcnt(4)" ::: "memory");   // buf0 ready, buf1 in flight
  __builtin_amdgcn_s_barrier();
  __builtin_amdgcn_sched_barrier(0);

  for (int kt = 0; kt < EMBED / 32; ++kt) {
    if (kt + 2 < EMBED / 32) STAGE((kt + 2) % 3, (kt + 2) * 32);
    const unsigned short* Ab = smem + (kt % 3) * 8192;
    const unsigned short* Bb = Ab + 4096;

    bf16x8 af[4], bfr[4];
#pragma unroll
    for (int i = 0; i < 4; ++i)
      af[i] = *(const bf16x8*)(Ab + (wm * 64 + i * 16 + c) * 32 + q * 8);
#pragma unroll
    for (int j = 0; j < 4; ++j)
      bfr[j] = *(const bf16x8*)(Bb + (wn * 64 + j * 16 + c) * 32 + q * 8);
#pragma unroll
    for (int i = 0; i < 4; ++i)
#pragma unroll
      for (int j = 0; j < 4; ++j)
        acc[i][j] = __builtin_amdgcn_mfma_f32_16x16x32_bf16(af[i], bfr[j], acc[i][j], 0, 0, 0);

    if (kt + 1 < EMBED / 32) {
      if (kt + 2 < EMBED / 32)
        asm volatile("s_waitcnt vmcnt(4)" ::: "memory");   // next buf done, one tile in flight
      else
        asm volatile("s_waitcnt vmcnt(0)" ::: "memory");   // last prefetch drains
      __builtin_amdgcn_s_barrier();
      __builtin_amdgcn_sched_barrier(0);
    }
  }

  if (z < 2) {
    const float sc = (z == 0) ? QSCALE : 1.0f;
#pragma unroll
    for (int i = 0; i < 4; ++i)
#pragma unroll
      for (int j = 0; j < 4; ++j)
#pragma unroll
        for (int r = 0; r < 4; ++r) {
          int m = m0 + wm * 64 + i * 16 + q * 4 + r;
          int col = n0 + wn * 64 + j * 16 + c;
          int b = m >> 11, s = m & 2047, h = col >> 6, d = col & 63;
          out[(size_t)((b * NH + h) * SEQ + s) * HD + d] = f2bf(acc[i][j][r] * sc);
        }
  } else {
    // V: transpose 128(s) x 128(d, 2 heads) tile through LDS -> [B,H,D,S]
    __syncthreads();
#pragma unroll
    for (int i = 0; i < 4; ++i)
#pragma unroll
      for (int j = 0; j < 4; ++j)
#pragma unroll
        for (int r = 0; r < 4; ++r)
          smem[(wm * 64 + i * 16 + q * 4 + r) * 130 + wn * 64 + j * 16 + c] =
              f2bf(acc[i][j][r]);
    __syncthreads();
    int n = tid >> 1;                 // 0..127 local d-col
    int sh = (tid & 1) * 64;          // s half
    int b = m0 >> 11, s0l = m0 & 2047;
    int h = blockIdx.y * 2 + (n >> 6), d = n & 63;
    unsigned short* dst = out + (size_t)((b * NH + h) * HD + d) * SEQ + s0l + sh;
#pragma unroll
    for (int g = 0; g < 8; ++g) {
      bf16x8 v;
#pragma unroll
      for (int e = 0; e < 8; ++e) v[e] = (short)smem[(sh + g * 8 + e) * 130 + n];
      *(bf16x8*)(dst + g * 8) = v;
    }
  }
}

// ---- out-projection GEMM: 64x128 tile, depth-2 prefetch, grid (64, 8) ----
// 512 blocks = 2/CU (was 1/CU at 128x128 — grid-starved, latency-bound).
__global__ __launch_bounds__(256) void gemm_out(
    const unsigned short* __restrict__ A,
    const unsigned short* __restrict__ Bw,
    const void* __restrict__ bias,
    void* __restrict__ out,
    const int* __restrict__ flagp)
{
  // per buf: As 64x32=2048 shorts | Bs 128x32=4096 shorts = 6144; 3 bufs = 36,864 B
  __shared__ __align__(16) unsigned short smem[18432];

  const int tid = threadIdx.x, lane = tid & 63, wave = tid >> 6;
  const int wm = wave >> 1, wn = wave & 1;     // wave covers 32 rows x 64 cols
  const int q = lane >> 4, c = lane & 15;
  const int m0 = blockIdx.x * 64, n0 = blockIdx.y * 128;

  f32x4 acc[2][4];
#pragma unroll
  for (int i = 0; i < 2; ++i)
#pragma unroll
    for (int j = 0; j < 4; ++j) acc[i][j] = (f32x4){0.f, 0.f, 0.f, 0.f};

  auto STAGE = [&](int buf, int k0) {   // 3 gload_lds per thread
    // A: 64 rows x 4 chunks = 256 slots, one per thread
    async_cp16(A + (size_t)(m0 + (tid >> 2)) * EMBED + k0 + (tid & 3) * 8,
               (void*)(smem + buf * 6144 + wave * 64 * 8));
    // B: 128 rows x 4 chunks = 512 slots, two per thread
#pragma unroll
    for (int j = 0; j < 2; ++j) {
      int s2 = j * 256 + tid;
      async_cp16(Bw + (size_t)(n0 + (s2 >> 2)) * EMBED + k0 + (s2 & 3) * 8,
                 (void*)(smem + buf * 6144 + 2048 + (j * 256 + wave * 64) * 8));
    }
  };

  STAGE(0, 0);
  STAGE(1, 32);
  asm volatile("s_waitcnt vmcnt(3)" ::: "memory");   // buf0 ready, buf1 in flight
  __builtin_amdgcn_s_barrier();
  __builtin_amdgcn_sched_barrier(0);

  for (int kt = 0; kt < EMBED / 32; ++kt) {
    if (kt + 2 < EMBED / 32) STAGE((kt + 2) % 3, (kt + 2) * 32);
    const unsigned short* Ab = smem + (kt % 3) * 6144;
    const unsigned short* Bb = Ab + 2048;

    bf16x8 af[2], bfr[4];
#pragma unroll
    for (int i = 0; i < 2; ++i)
      af[i] = *(const bf16x8*)(Ab + (wm * 32 + i * 16 + c) * 32 + q * 8);
#pragma unroll
    for (int j = 0; j < 4; ++j)
      bfr[j] = *(const bf16x8*)(Bb + (wn * 64 + j * 16 + c) * 32 + q * 8);
#pragma unroll
    for (int i = 0; i < 2; ++i)
#pragma unroll
      for (int j = 0; j < 4; ++j)
        acc[i][j] = __builtin_amdgcn_mfma_f32_16x16x32_bf16(af[i], bfr[j], acc[i][j], 0, 0, 0);

    if (kt + 1 < EMBED / 32) {
      if (kt + 2 < EMBED / 32)
        asm volatile("s_waitcnt vmcnt(3)" ::: "memory");
      else
        asm volatile("s_waitcnt vmcnt(0)" ::: "memory");
      __builtin_amdgcn_s_barrier();
      __builtin_amdgcn_sched_barrier(0);
    }
  }

  const bool isbf = (*flagp != 0);
#pragma unroll
  for (int i = 0; i < 2; ++i)
#pragma unroll
    for (int j = 0; j < 4; ++j)
#pragma unroll
      for (int r = 0; r < 4; ++r) {
        int m = m0 + wm * 32 + i * 16 + q * 4 + r;
        int col = n0 + wn * 64 + j * 16 + c;
        float v = acc[i][j][r];
        v += isbf ? bf2f(((const unsigned short*)bias)[col]) : ((const float*)bias)[col];
        if (isnan(v)) v = 777.0f;     // marker
        if (isbf) ((unsigned short*)out)[(size_t)m * EMBED + col] = f2bf(v);
        else      ((float*)out)[(size_t)m * EMBED + col] = v;
      }
}

// ---- flash attention r21 = r12/r17 exact: grid (16,16,2)=512 blocks,
// 4 waves x 32 qrows. Permuted-V LDS (PV vf = one ds_read_b128), packbf
// P-pack, l via ones-MFMA, K-frag hoist, running pointers, 1 barrier/tile.
__global__ __launch_bounds__(256) void attn_kernel(
    const unsigned short* __restrict__ Qb,
    const unsigned short* __restrict__ Kb,
    const unsigned short* __restrict__ Vtb,
    unsigned short* __restrict__ Ob)
{
  __shared__ __align__(16) unsigned short Kt[2][64][72];
  __shared__ __align__(16) unsigned short Vs[2][64][72];

  const int tid = threadIdx.x;
  const int lane = tid & 63;
  const int wave = tid >> 6;
  const int q = lane >> 4, c = lane & 15;
  const int b = blockIdx.z, h = blockIdx.y;
  const int q0 = blockIdx.x * 128 + wave * 32;

  const unsigned short* Qh = Qb + ((size_t)(b * NH + h) * SEQ) * HD;
  const unsigned short* Kh = Kb + ((size_t)(b * NH + h) * SEQ) * HD;
  const unsigned short* Vh = Vtb + ((size_t)(b * NH + h) * HD) * SEQ;

  // Q B-operand frags for two 16-row groups (n=lane&15=qrow, k=d=quad*8+j)
  bf16x8 qflA = *(const bf16x8*)(Qh + (q0 + c) * HD + q * 8);
  bf16x8 qfhA = *(const bf16x8*)(Qh + (q0 + c) * HD + 32 + q * 8);
  bf16x8 qflB = *(const bf16x8*)(Qh + (q0 + 16 + c) * HD + q * 8);
  bf16x8 qfhB = *(const bf16x8*)(Qh + (q0 + 16 + c) * HD + 32 + q * 8);

  f32x4 oA[4], oB[4];
#pragma unroll
  for (int t = 0; t < 4; ++t) { oA[t] = (f32x4){0.f,0.f,0.f,0.f}; oB[t] = (f32x4){0.f,0.f,0.f,0.f}; }
  f32x4 lA = (f32x4){0.f,0.f,0.f,0.f}, lB = (f32x4){0.f,0.f,0.f,0.f};

  bf16x8 ones;
#pragma unroll
  for (int e = 0; e < 8; ++e) ones[e] = (short)0x3F80;

  const int r0 = tid >> 3;          // 0..31 (d-row for V, key-row for K)
  const int t7 = tid & 7;
  const int ch0 = t7 * 8;           // source 8-elem chunk
  // permuted dest 8B-unit for source chunk m=2*t7 (second half goes to u0+2)
  const int u0 = 8 * (t7 >> 2) + 4 * (t7 & 1) + ((t7 >> 1) & 1);

  // running global pointers (stride: K rows 64*HD shorts, V cols 64 shorts)
  const bf16x8* pK0 = (const bf16x8*)(Kh + (size_t)r0 * HD + ch0);
  const bf16x8* pK1 = (const bf16x8*)(Kh + (size_t)(32 + r0) * HD + ch0);
  const bf16x8* pV0 = (const bf16x8*)(Vh + (size_t)r0 * SEQ + ch0);
  const bf16x8* pV1 = (const bf16x8*)(Vh + (size_t)(32 + r0) * SEQ + ch0);

  bf16x8 kr0, kr1, vr0, vr1;
  // prefetch + stage tile 0
  kr0 = *pK0; pK0 += (64 * HD) / 8;
  kr1 = *pK1; pK1 += (64 * HD) / 8;
  vr0 = *pV0; pV0 += 64 / 8;
  vr1 = *pV1; pV1 += 64 / 8;
  *(bf16x8*)(&Kt[0][r0][ch0]) = kr0;
  *(bf16x8*)(&Kt[0][32 + r0][ch0]) = kr1;
  {
    bf16x4 lo0 = __builtin_shufflevector(vr0, vr0, 0, 1, 2, 3);
    bf16x4 hi0 = __builtin_shufflevector(vr0, vr0, 4, 5, 6, 7);
    bf16x4 lo1 = __builtin_shufflevector(vr1, vr1, 0, 1, 2, 3);
    bf16x4 hi1 = __builtin_shufflevector(vr1, vr1, 4, 5, 6, 7);
    *(bf16x4*)(&Vs[0][r0][u0 * 4]) = lo0;
    *(bf16x4*)(&Vs[0][r0][u0 * 4 + 8]) = hi0;
    *(bf16x4*)(&Vs[0][32 + r0][u0 * 4]) = lo1;
    *(bf16x4*)(&Vs[0][32 + r0][u0 * 4 + 8]) = hi1;
  }

  for (int kt = 0; kt < SEQ / 64; ++kt) {
    const int p = kt & 1;
    __syncthreads();
    if (kt + 1 < SEQ / 64) {        // issue next-tile loads early (latency overlap)
      kr0 = *pK0; pK0 += (64 * HD) / 8;
      kr1 = *pK1; pK1 += (64 * HD) / 8;
      vr0 = *pV0; pV0 += 64 / 8;
      vr1 = *pV1; pV1 += 64 / 8;
    }

    // hoist all 8 K-frags: back-to-back LDS reads pipeline
    bf16x8 kf0[4], kf1[4];
#pragma unroll
    for (int s = 0; s < 4; ++s) {
      kf0[s] = *(const bf16x8*)(&Kt[p][s * 16 + c][q * 8]);
      kf1[s] = *(const bf16x8*)(&Kt[p][s * 16 + c][32 + q * 8]);
    }

#pragma unroll
    for (int g = 0; g < 2; ++g) {
      u32x4 pa, pb;
#pragma unroll
      for (int s2 = 0; s2 < 2; ++s2) {
        const int s = g * 2 + s2;
        f32x4 zA = {0.f, 0.f, 0.f, 0.f};
        f32x4 zB = {0.f, 0.f, 0.f, 0.f};
        zA = __builtin_amdgcn_mfma_f32_16x16x32_bf16(kf0[s], qflA, zA, 0, 0, 0);
        zA = __builtin_amdgcn_mfma_f32_16x16x32_bf16(kf1[s], qfhA, zA, 0, 0, 0);
        zB = __builtin_amdgcn_mfma_f32_16x16x32_bf16(kf0[s], qflB, zB, 0, 0, 0);
        zB = __builtin_amdgcn_mfma_f32_16x16x32_bf16(kf1[s], qfhB, zB, 0, 0, 0);
        float a0 = __builtin_amdgcn_exp2f(zA[0]);
        float a1 = __builtin_amdgcn_exp2f(zA[1]);
        float a2 = __builtin_amdgcn_exp2f(zA[2]);
        float a3 = __builtin_amdgcn_exp2f(zA[3]);
        float b0 = __builtin_amdgcn_exp2f(zB[0]);
        float b1 = __builtin_amdgcn_exp2f(zB[1]);
        float b2 = __builtin_amdgcn_exp2f(zB[2]);
        float b3 = __builtin_amdgcn_exp2f(zB[3]);
        pa[s2 * 2]     = packbf(a0, a1);   // = trunc(a0) | trunc(a1)<<16
        pa[s2 * 2 + 1] = packbf(a2, a3);
        pb[s2 * 2]     = packbf(b0, b1);
        pb[s2 * 2 + 1] = packbf(b2, b3);
      }
      bf16x8 pfA = __builtin_bit_cast(bf16x8, pa);
      bf16x8 pfB = __builtin_bit_cast(bf16x8, pb);
      __builtin_amdgcn_s_setprio(1);
      lA = __builtin_amdgcn_mfma_f32_16x16x32_bf16(pfA, ones, lA, 0, 0, 0);
      lB = __builtin_amdgcn_mfma_f32_16x16x32_bf16(pfB, ones, lB, 0, 0, 0);
#pragma unroll
      for (int t = 0; t < 4; ++t) {
        bf16x8 vf = *(const bf16x8*)(&Vs[p][t * 16 + c][(g * 4 + q) * 8]);
        oA[t] = __builtin_amdgcn_mfma_f32_16x16x32_bf16(pfA, vf, oA[t], 0, 0, 0);
        oB[t] = __builtin_amdgcn_mfma_f32_16x16x32_bf16(pfB, vf, oB[t], 0, 0, 0);
      }
      __builtin_amdgcn_s_setprio(0);
    }

    if (kt + 1 < SEQ / 64) {        // stage next tile into the other buffer
      *(bf16x8*)(&Kt[1 - p][r0][ch0]) = kr0;
      *(bf16x8*)(&Kt[1 - p][32 + r0][ch0]) = kr1;
      bf16x4 lo0 = __builtin_shufflevector(vr0, vr0, 0, 1, 2, 3);
      bf16x4 hi0 = __builtin_shufflevector(vr0, vr0, 4, 5, 6, 7);
      bf16x4 lo1 = __builtin_shufflevector(vr1, vr1, 0, 1, 2, 3);
      bf16x4 hi1 = __builtin_shufflevector(vr1, vr1, 4, 5, 6, 7);
      *(bf16x4*)(&Vs[1 - p][r0][u0 * 4]) = lo0;
      *(bf16x4*)(&Vs[1 - p][r0][u0 * 4 + 8]) = hi0;
      *(bf16x4*)(&Vs[1 - p][32 + r0][u0 * 4]) = lo1;
      *(bf16x4*)(&Vs[1 - p][32 + r0][u0 * 4 + 8]) = hi1;
    }
  }

  // l lands in the same C-layout as o: lane reg r holds l for row q*4+r.
  float invA[4], invB[4];
#pragma unroll
  for (int r = 0; r < 4; ++r) { invA[r] = 1.0f / lA[r]; invB[r] = 1.0f / lB[r]; }
#pragma unroll
  for (int t = 0; t < 4; ++t)
#pragma unroll
    for (int r = 0; r < 4; ++r) {
      int col = h * HD + t * 16 + c;
      int srowA = q0 + q * 4 + r;
      float vA = oA[t][r] * invA[r];
      if (isnan(vA)) vA = 77.0f;    // marker
      Ob[((size_t)(b * SEQ + srowA)) * EMBED + col] = f2bf(vA);
      int srowB = q0 + 16 + q * 4 + r;
      float vB = oB[t][r] * invB[r];
      if (isnan(vB)) vB = 77.0f;    // marker
      Ob[((size_t)(b * SEQ + srowB)) * EMBED + col] = f2bf(vB);
    }
}

// ---- fallback GEMM (round-3 proven, direct global loads) ----
__device__ inline bf16x8 load8(const void* p, int idx, bool isbf) {
  if (isbf) return *(const bf16x8*)((const unsigned short*)p + idx);
  const float* f = (const float*)p + idx;
  bf16x8 r;
#pragma unroll
  for (int i = 0; i < 8; ++i) r[i] = (short)f2bf(f[i]);
  return r;
}
__global__ __launch_bounds__(256) void gemm_bt(
    const void* __restrict__ A, const void* __restrict__ Bw,
    const void* __restrict__ bias, void* __restrict__ out,
    const int* __restrict__ flagp, int mode, float scale)
{
  const bool isbf = (*flagp != 0);
  const bool a_isbf = isbf || (mode == 0);
  const int lane = threadIdx.x & 63;
  const int wave = threadIdx.x >> 6;
  const int tile = blockIdx.x * 4 + wave;
  const int mt = tile >> 4, nt = tile & 15;
  const int q = lane >> 4, c = lane & 15;
  const int m0 = mt * 16, n0 = nt * 64;

  f32x4 acc[4];
#pragma unroll
  for (int t = 0; t < 4; ++t) acc[t] = (f32x4){0.f, 0.f, 0.f, 0.f};

  for (int k0 = 0; k0 < EMBED; k0 += 32) {
    bf16x8 a = load8(A, (m0 + c) * EMBED + k0 + q * 8, a_isbf);
#pragma unroll
    for (int t = 0; t < 4; ++t) {
      bf16x8 b = load8(Bw, (n0 + t * 16 + c) * EMBED + k0 + q * 8, isbf);
      acc[t] = __builtin_amdgcn_mfma_f32_16x16x32_bf16(a, b, acc[t], 0, 0, 0);
    }
  }
#pragma unroll
  for (int t = 0; t < 4; ++t)
#pragma unroll
    for (int r = 0; r < 4; ++r) {
      float v = acc[t][r] * scale;
      int row = m0 + q * 4 + r, col = n0 + t * 16 + c;
      if (mode == 0) {
        v += isbf ? bf2f(((const unsigned short*)bias)[col]) : ((const float*)bias)[col];
        if (isbf) ((unsigned short*)out)[row * EMBED + col] = f2bf(v);
        else      ((float*)out)[row * EMBED + col] = v;
      } else {
        int b = row >> 11, s = row & 2047, h = col >> 6, d = col & 63;
        if (mode == 1) ((unsigned short*)out)[(((b * NH + h) * SEQ) + s) * HD + d] = f2bf(v);
        else           ((unsigned short*)out)[(((b * NH + h) * HD) + d) * SEQ + s] = f2bf(v);
      }
    }
}

extern "C" void kernel_launch(void* const* d_in, const int* in_sizes, int n_in,
                              void* d_out, int out_size, void* d_ws, size_t ws_size,
                              hipStream_t stream) {
  const void* xq = d_in[0]; const void* xk = d_in[1]; const void* xv = d_in[2];
  const void* Wq = d_in[3]; const void* Wk = d_in[4]; const void* Wv = d_in[5];
  const void* Wo = d_in[6]; const void* bo = d_in[7];

  const size_t NEL = (size_t)BATCH * SEQ * EMBED;
  const size_t WEL = (size_t)EMBED * EMBED;
  unsigned short* base = (unsigned short*)d_ws;

  unsigned short* Xq = base;
  unsigned short* Xk = Xq + NEL;
  unsigned short* Xv = Xk + NEL;
  unsigned short* Wqb = Xv + NEL;
  unsigned short* Wkb = Wqb + WEL;
  unsigned short* Wvb = Wkb + WEL;
  unsigned short* Wob = Wvb + WEL;
  unsigned short* Q  = Wob + WEL;
  unsigned short* K  = Q + NEL;
  unsigned short* Vt = K + NEL;
  unsigned short* AO = Xq;                  // alias: Xq dead after QKV GEMM
  int* flagF = (int*)(Vt + NEL);
  size_t need = ((char*)(flagF + 16)) - (char*)d_ws;

  if (ws_size >= need) {
    PackPtrs pp;
    pp.src[0] = xq; pp.src[1] = xk; pp.src[2] = xv;
    pp.src[3] = Wq; pp.src[4] = Wk; pp.src[5] = Wv; pp.src[6] = Wo;
    pp.dst[0] = Xq; pp.dst[1] = Xk; pp.dst[2] = Xv;
    pp.dst[3] = Wqb; pp.dst[4] = Wkb; pp.dst[5] = Wvb; pp.dst[6] = Wob;
    pack_all<<<8192, 256, 0, stream>>>(pp, flagF);   // self-sniffs; writes flagF

    QkvArgs qa;
    qa.A[0] = Xq; qa.A[1] = Xk; qa.A[2] = Xv;
    qa.W[0] = Wqb; qa.W[1] = Wkb; qa.W[2] = Wvb;
    qa.out[0] = Q; qa.out[1] = K; qa.out[2] = Vt;
    gemm_qkv<<<dim3(32, 8, 3), 256, 0, stream>>>(qa);
    attn_kernel<<<dim3(SEQ / 128, NH, BATCH), 256, 0, stream>>>(Q, K, Vt, AO);
    gemm_out<<<dim3(64, 8), 256, 0, stream>>>(AO, Wob, bo, d_out, flagF);
  } else {
    unsigned short* Qf  = base;
    unsigned short* Kf  = Qf + NEL;
    unsigned short* Vtf = Kf + NEL;
    unsigned short* AOf = Vtf + NEL;
    int* flag = (int*)(AOf + NEL);
    detect_kernel<<<1, 256, 0, stream>>>((const unsigned int*)xq, flag);
    dim3 gblk(1024, 1, 1);
    gemm_bt<<<gblk, 256, 0, stream>>>(xq, Wq, nullptr, Qf, flag, 1, QSCALE);
    gemm_bt<<<gblk, 256, 0, stream>>>(xk, Wk, nullptr, Kf, flag, 1, 1.0f);
    gemm_bt<<<gblk, 256, 0, stream>>>(xv, Wv, nullptr, Vtf, flag, 2, 1.0f);
    attn_kernel<<<dim3(SEQ / 128, NH, BATCH), 256, 0, stream>>>(Qf, Kf, Vtf, AOf);
    gemm_bt<<<gblk, 256, 0, stream>>>(AOf, Wo, bo, d_out, flag, 0, 1.0f);
  }
}